// Round 1
// 576.954 us; speedup vs baseline: 1.1988x; 1.1988x over previous
//
#include <hip/hip_runtime.h>

#define DIM 64
#define RPB 2048              // rows per coarse bucket
#define RPB_SHIFT 11
#define NBMAX 512             // max coarse buckets supported
#define CHUNK 4096            // edges per bin_edges block
#define EPT 16                // edges per thread in bin_edges (CHUNK/256)
#define CAPT 70               // records per thread in sort (cap = 70*256 = 17920)
#define NPG 8                 // nodes per 16-lane group in gather

typedef unsigned long long u64;
typedef unsigned int u32;
typedef unsigned short u16;
typedef float f4v __attribute__((ext_vector_type(4)));
typedef _Float16 h4 __attribute__((ext_vector_type(4)));

// ---------------- idx width detection (int64 vs int32 layout) --------------
__global__ void detect_idx_width(const unsigned int* __restrict__ idx_words,
                                 int* __restrict__ flag) {
    __shared__ unsigned int s_or[256];
    unsigned int acc = 0;
    for (int i = threadIdx.x; i < 4096; i += blockDim.x)
        acc |= idx_words[2 * i + 1];
    s_or[threadIdx.x] = acc;
    __syncthreads();
    for (int s = 128; s > 0; s >>= 1) {
        if (threadIdx.x < s) s_or[threadIdx.x] |= s_or[threadIdx.x + s];
        __syncthreads();
    }
    if (threadIdx.x == 0) *flag = (s_or[0] == 0) ? 1 : 0;
}

__device__ __forceinline__ int load_idx(const void* ei, int use64, long long i) {
    return use64 ? (int)((const long long*)ei)[i] : ((const int*)ei)[i];
}

// ---------------- embedding f32 -> f16 conversion (nt reads) ---------------
__global__ __launch_bounds__(256) void convert_emb(const f4v* __restrict__ u4,
                                                   const f4v* __restrict__ i4,
                                                   long long usz4, long long tot4,
                                                   h4* __restrict__ dst) {
    long long stride = (long long)gridDim.x * blockDim.x;
    for (long long idx = (long long)blockIdx.x * blockDim.x + threadIdx.x;
         idx < tot4; idx += stride) {
        const f4v* src = (idx < usz4) ? (u4 + idx) : (i4 + (idx - usz4));
        f4v f = __builtin_nontemporal_load(src);
        h4 o;
        o.x = (_Float16)f.x; o.y = (_Float16)f.y;
        o.z = (_Float16)f.z; o.w = (_Float16)f.w;
        dst[idx] = o;
    }
}

// ---------------- pass 1: coarse histogram (LDS-assisted) ------------------
__global__ __launch_bounds__(256) void hist_coarse(const void* __restrict__ ei,
                                                   const int* __restrict__ flag,
                                                   int* __restrict__ counts,
                                                   int num_edges) {
    __shared__ int h[NBMAX];
    for (int b = threadIdx.x; b < NBMAX; b += 256) h[b] = 0;
    __syncthreads();
    int use64 = *flag;
    long long stride = (long long)gridDim.x * 256;
    for (long long e = (long long)blockIdx.x * 256 + threadIdx.x; e < num_edges; e += stride) {
        int r = load_idx(ei, use64, e);
        atomicAdd(&h[r >> RPB_SHIFT], 1);
    }
    __syncthreads();
    for (int b = threadIdx.x; b < NBMAX; b += 256)
        if (h[b]) atomicAdd(&counts[b], h[b]);
}

// ---------------- pass 2: scan of 512 bucket counts (1 block) --------------
__global__ __launch_bounds__(256) void scan512(const int* __restrict__ counts,
                                               int* __restrict__ offs,
                                               int* __restrict__ gcursor,
                                               int* __restrict__ offs2, int nbkt) {
    __shared__ int ps[256];
    int t = threadIdx.x;
    int h0 = counts[2 * t], h1 = counts[2 * t + 1];
    ps[t] = h0 + h1;
    __syncthreads();
    for (int st = 1; st < 256; st <<= 1) {
        int add = (t >= st) ? ps[t - st] : 0;
        __syncthreads();
        ps[t] += add;
        __syncthreads();
    }
    int ep = (t > 0) ? ps[t - 1] : 0;
    offs[2 * t] = ep;          gcursor[2 * t] = ep;
    offs[2 * t + 1] = ep + h0; gcursor[2 * t + 1] = ep + h0;
    if (t == 255) {
        offs[NBMAX] = ps[255];
        offs2[(long long)nbkt << RPB_SHIFT] = ps[255];   // tail sentinel = num_edges
    }
}

// ---------------- pass 3: LDS-staged coarse binning ------------------------
// record: [w:32][rowlocal:11][col:20]
__global__ __launch_bounds__(256) void bin_edges(const void* __restrict__ ei,
                                                 const float* __restrict__ vals,
                                                 const int* __restrict__ flag,
                                                 int* __restrict__ gcursor,
                                                 u64* __restrict__ recs,
                                                 int num_edges) {
    __shared__ u32 hist[NBMAX];     // counts, then running cursor
    __shared__ u32 scanL[NBMAX];
    __shared__ u32 gbase[NBMAX];
    __shared__ u32 ps[256];
    __shared__ u64 payload[CHUNK];
    __shared__ u16 bidv[CHUNK];

    int tid = threadIdx.x;
    long long base = (long long)blockIdx.x * CHUNK;
    int n = (int)min((long long)CHUNK, (long long)num_edges - base);
    int use64 = *flag;

    for (int b = tid; b < NBMAX; b += 256) hist[b] = 0;
    __syncthreads();

    int rows_[EPT]; int cols_[EPT]; float ws_[EPT];
    #pragma unroll
    for (int i = 0; i < EPT; ++i) {
        int j = tid + i * 256;
        rows_[i] = -1;
        if (j < n) {
            long long e = base + j;
            rows_[i] = load_idx(ei, use64, e);
            cols_[i] = load_idx(ei, use64, (long long)num_edges + e);
            ws_[i]   = vals[e];
            atomicAdd(&hist[rows_[i] >> RPB_SHIFT], 1u);
        }
    }
    __syncthreads();

    // exclusive scan of 512 counts (pair-per-thread Hillis-Steele)
    u32 h0 = hist[2 * tid], h1 = hist[2 * tid + 1];
    ps[tid] = h0 + h1;
    __syncthreads();
    for (int st = 1; st < 256; st <<= 1) {
        u32 add = (tid >= st) ? ps[tid - st] : 0;
        __syncthreads();
        ps[tid] += add;
        __syncthreads();
    }
    u32 ep = (tid > 0) ? ps[tid - 1] : 0;
    scanL[2 * tid] = ep;
    scanL[2 * tid + 1] = ep + h0;
    __syncthreads();

    // reserve global space per bucket
    for (int b = tid; b < NBMAX; b += 256) {
        u32 c = hist[b];
        gbase[b] = c ? (u32)atomicAdd(&gcursor[b], (int)c) : 0u;
    }
    __syncthreads();
    for (int b = tid; b < NBMAX; b += 256) hist[b] = scanL[b];
    __syncthreads();

    // scatter records into LDS ordered by bucket
    #pragma unroll
    for (int i = 0; i < EPT; ++i) {
        if (rows_[i] >= 0) {
            int b = rows_[i] >> RPB_SHIFT;
            u32 pos = atomicAdd(&hist[b], 1u);
            u32 rl = (u32)(rows_[i] & (RPB - 1));
            payload[pos] = ((u64)__float_as_uint(ws_[i]) << 32) | (rl << 20) | (u32)cols_[i];
            bidv[pos] = (u16)b;
        }
    }
    __syncthreads();

    // flush: consecutive LDS slots -> consecutive global slots per bucket run
    for (int j = tid; j < n; j += 256) {
        u64 rec = payload[j];
        int b = bidv[j];
        recs[gbase[b] + (u32)j - scanL[b]] = rec;
    }
}

// ---------------- pass 4: per-bucket exact sort (register-staged) ----------
__global__ __launch_bounds__(256, 1) void sort_bucket(const int* __restrict__ offs,
                                                      u64* __restrict__ recs,
                                                      int* __restrict__ offs2) {
    __shared__ u32 bins[RPB];    // 8 KB
    __shared__ u32 ps[256];
    int b = blockIdx.x;
    int t = threadIdx.x;
    int beg = offs[b], end = offs[b + 1];
    int cnt = end - beg;
    int row0 = b << RPB_SHIFT;

    if (cnt > CAPT * 256) {
        // practically unreachable; leave coarse-sorted, sentinel offsets
        for (int i = t; i < RPB; i += 256) offs2[row0 + i] = -(b + 1);
        return;
    }

    // stage the whole bucket in registers (static indexing -> stays in VGPRs)
    u64 r_[CAPT];
    #pragma unroll
    for (int k = 0; k < CAPT; ++k) {
        int j = t + k * 256;
        r_[k] = (j < cnt) ? recs[beg + j] : 0ull;
    }
    for (int i = t; i < RPB; i += 256) bins[i] = 0;
    __syncthreads();

    #pragma unroll
    for (int k = 0; k < CAPT; ++k) {
        int j = t + k * 256;
        if (j < cnt) atomicAdd(&bins[(u32)(r_[k] >> 20) & (RPB - 1)], 1u);
    }
    __syncthreads();

    // scan 2048 bins: thread owns 8 consecutive
    u32 c0[8]; u32 s = 0;
    #pragma unroll
    for (int i = 0; i < 8; ++i) { c0[i] = bins[t * 8 + i]; s += c0[i]; }
    ps[t] = s;
    __syncthreads();
    for (int st = 1; st < 256; st <<= 1) {
        u32 add = (t >= st) ? ps[t - st] : 0;
        __syncthreads();
        ps[t] += add;
        __syncthreads();
    }
    u32 ex = (t > 0) ? ps[t - 1] : 0;
    #pragma unroll
    for (int i = 0; i < 8; ++i) {
        bins[t * 8 + i] = ex;
        offs2[row0 + t * 8 + i] = beg + (int)ex;
        ex += c0[i];
    }
    __syncthreads();

    // in-place scatter to exact positions (all records already in registers)
    #pragma unroll
    for (int k = 0; k < CAPT; ++k) {
        int j = t + k * 256;
        if (j < cnt) {
            u32 rl = (u32)(r_[k] >> 20) & (RPB - 1);
            u32 pos = atomicAdd(&bins[rl], 1u);
            recs[beg + pos] = r_[k];
        }
    }
}

// ---------------- pass 5 (fp16 table): one 16-lane group per node strip ----
// Each 16-lane group owns NPG consecutive nodes; lane l16 owns dims
// [4*l16, 4*l16+4). No cross-lane reduce needed; store is a coalesced
// 256B float4 row per node. Edge loop unrolled 4-wide: all rec loads and
// all table loads issue before the FMAs (deep MLP instead of the old
// offs2->rec->table serial chain per 8-edge wave).
__global__ __launch_bounds__(256) void gather_nodes_h(const int* __restrict__ offs,
                                                      const int* __restrict__ offs2,
                                                      const u64* __restrict__ recs,
                                                      const h4* __restrict__ hemb4,
                                                      float* __restrict__ out,
                                                      int num_nodes) {
    int l16 = threadIdx.x & 15;
    int n0  = (blockIdx.x * 16 + (threadIdx.x >> 4)) * NPG;

    for (int nn = 0; nn < NPG; ++nn) {
        int node = n0 + nn;
        if (node >= num_nodes) return;

        int beg = offs2[node];
        int end = offs2[node + 1];
        if (beg < 0) { int b = node >> RPB_SHIFT; beg = offs[b]; end = offs[b + 1]; }
        else if (end < 0) { end = offs[(node >> RPB_SHIFT) + 1]; }
        u32 rl = (u32)(node & (RPB - 1));

        float4 a0 = make_float4(0.f, 0.f, 0.f, 0.f);
        float4 a1 = make_float4(0.f, 0.f, 0.f, 0.f);
        float4 a2 = make_float4(0.f, 0.f, 0.f, 0.f);
        float4 a3 = make_float4(0.f, 0.f, 0.f, 0.f);

        for (int i = beg; i < end; i += 4) {
            int last = end - 1;
            int e1 = min(i + 1, last);
            int e2 = min(i + 2, last);
            int e3 = min(i + 3, last);
            u64 s0 = __builtin_nontemporal_load(&recs[i]);
            u64 s1 = __builtin_nontemporal_load(&recs[e1]);
            u64 s2 = __builtin_nontemporal_load(&recs[e2]);
            u64 s3 = __builtin_nontemporal_load(&recs[e3]);

            u32 c0 = (u32)s0 & 0xFFFFFu;
            u32 c1 = (u32)s1 & 0xFFFFFu;
            u32 c2 = (u32)s2 & 0xFFFFFu;
            u32 c3 = (u32)s3 & 0xFFFFFu;
            h4 v0 = hemb4[(c0 << 4) + l16];
            h4 v1 = hemb4[(c1 << 4) + l16];
            h4 v2 = hemb4[(c2 << 4) + l16];
            h4 v3 = hemb4[(c3 << 4) + l16];

            u32 r0 = ((u32)(s0 >> 20)) & (RPB - 1);
            u32 r1 = ((u32)(s1 >> 20)) & (RPB - 1);
            u32 r2 = ((u32)(s2 >> 20)) & (RPB - 1);
            u32 r3 = ((u32)(s3 >> 20)) & (RPB - 1);
            // s0 is always in-bounds (loop condition); clamped dups must be
            // masked by the bound check since they belong to the same node.
            float w0 = (r0 == rl)                    ? __uint_as_float((u32)(s0 >> 32)) : 0.f;
            float w1 = ((r1 == rl) & (i + 1 < end))  ? __uint_as_float((u32)(s1 >> 32)) : 0.f;
            float w2 = ((r2 == rl) & (i + 2 < end))  ? __uint_as_float((u32)(s2 >> 32)) : 0.f;
            float w3 = ((r3 == rl) & (i + 3 < end))  ? __uint_as_float((u32)(s3 >> 32)) : 0.f;

            a0.x += w0 * (float)v0.x; a0.y += w0 * (float)v0.y;
            a0.z += w0 * (float)v0.z; a0.w += w0 * (float)v0.w;
            a1.x += w1 * (float)v1.x; a1.y += w1 * (float)v1.y;
            a1.z += w1 * (float)v1.z; a1.w += w1 * (float)v1.w;
            a2.x += w2 * (float)v2.x; a2.y += w2 * (float)v2.y;
            a2.z += w2 * (float)v2.z; a2.w += w2 * (float)v2.w;
            a3.x += w3 * (float)v3.x; a3.y += w3 * (float)v3.y;
            a3.z += w3 * (float)v3.z; a3.w += w3 * (float)v3.w;
        }

        a0.x += a1.x; a0.y += a1.y; a0.z += a1.z; a0.w += a1.w;
        a2.x += a3.x; a2.y += a3.y; a2.z += a3.z; a2.w += a3.w;
        a0.x += a2.x; a0.y += a2.y; a0.z += a2.z; a0.w += a2.w;

        f4v o; o.x = a0.x; o.y = a0.y; o.z = a0.z; o.w = a0.w;
        __builtin_nontemporal_store(o, (f4v*)out + ((long long)node << 4) + l16);
    }
}

// ---------------- pass 5 (f32 fallback): one wave per node -----------------
__device__ __forceinline__ void gstep(u64 s, u32 rl,
                                      const float* __restrict__ users,
                                      const float* __restrict__ items_m,
                                      int num_users, int l16, float4& a) {
    int c = (int)(s & 0xFFFFFu);
    float w = __uint_as_float((u32)(s >> 32));
    w = (((u32)(s >> 20) & (RPB - 1)) == rl) ? w : 0.f;
    const float* p = ((c < num_users) ? users : items_m) + ((u32)c << 6);
    float4 m = reinterpret_cast<const float4*>(p)[l16];
    a.x += w * m.x; a.y += w * m.y; a.z += w * m.z; a.w += w * m.w;
}

__global__ __launch_bounds__(256) void gather_nodes(const int* __restrict__ offs,
                                                    const int* __restrict__ offs2,
                                                    const u64* __restrict__ recs,
                                                    const float* __restrict__ users,
                                                    const float* __restrict__ items_m,
                                                    float* __restrict__ out,
                                                    int num_users, int num_nodes) {
    int node = blockIdx.x * (blockDim.x >> 6) + (threadIdx.x >> 6);
    int lane = threadIdx.x & 63;
    if (node >= num_nodes) return;
    int q   = lane >> 4;
    int l16 = lane & 15;

    int beg = offs2[node];
    int end = offs2[node + 1];
    if (beg < 0) { int b = node >> RPB_SHIFT; beg = offs[b]; end = offs[b + 1]; }
    else if (end < 0) { end = offs[(node >> RPB_SHIFT) + 1]; }
    u32 rl = (u32)(node & (RPB - 1));

    float4 a0 = make_float4(0.f, 0.f, 0.f, 0.f);
    float4 a1 = make_float4(0.f, 0.f, 0.f, 0.f);

    int i = beg + q;
    for (; i + 4 < end; i += 8) {
        u64 s0 = recs[i];
        u64 s1 = recs[i + 4];
        gstep(s0, rl, users, items_m, num_users, l16, a0);
        gstep(s1, rl, users, items_m, num_users, l16, a1);
    }
    if (i < end) {
        u64 s0 = recs[i];
        gstep(s0, rl, users, items_m, num_users, l16, a0);
    }
    a0.x += a1.x; a0.y += a1.y; a0.z += a1.z; a0.w += a1.w;

    for (int msk = 16; msk <= 32; msk <<= 1) {
        a0.x += __shfl_xor(a0.x, msk, 64);
        a0.y += __shfl_xor(a0.y, msk, 64);
        a0.z += __shfl_xor(a0.z, msk, 64);
        a0.w += __shfl_xor(a0.w, msk, 64);
    }
    if (q == 0)
        reinterpret_cast<float4*>(out)[(long long)node * 16 + l16] = a0;
}

// ---------------- fallback: R1 atomic scatter ------------------------------
__global__ __launch_bounds__(256) void scatter_edges(const void* __restrict__ edge_index,
                                                     const float* __restrict__ vals,
                                                     const float* __restrict__ users,
                                                     const float* __restrict__ items,
                                                     float* __restrict__ out,
                                                     const int* __restrict__ idx64_flag,
                                                     int num_users, int num_edges) {
    long long gid = (long long)blockIdx.x * blockDim.x + threadIdx.x;
    long long e = gid >> 4;
    int lane = (int)(gid & 15);
    if (e >= num_edges) return;
    int use64 = *idx64_flag;
    int r = load_idx(edge_index, use64, e);
    int c = load_idx(edge_index, use64, (long long)num_edges + e);
    float w = vals[e];
    const float* src = (c < num_users)
        ? (users + (long long)c * DIM)
        : (items + (long long)(c - num_users) * DIM);
    float4 m = reinterpret_cast<const float4*>(src)[lane];
    float* dst = out + (long long)r * DIM + lane * 4;
    unsafeAtomicAdd(dst + 0, m.x * w);
    unsafeAtomicAdd(dst + 1, m.y * w);
    unsafeAtomicAdd(dst + 2, m.z * w);
    unsafeAtomicAdd(dst + 3, m.w * w);
}

extern "C" void kernel_launch(void* const* d_in, const int* in_sizes, int n_in,
                              void* d_out, int out_size, void* d_ws, size_t ws_size,
                              hipStream_t stream) {
    const float* users = (const float*)d_in[0];
    const float* items = (const float*)d_in[1];
    const void*  eidx  = d_in[2];
    const float* vals  = (const float*)d_in[3];
    float* out = (float*)d_out;

    int num_users = in_sizes[0] / DIM;               // 600000
    int num_items = in_sizes[1] / DIM;               // 400000
    int num_nodes = num_users + num_items;           // 1000000
    int num_edges = in_sizes[3];                     // 8000000
    int nbkt = (num_nodes + RPB - 1) >> RPB_SHIFT;   // 489

    // workspace layout
    size_t off = 0;
    auto alloc = [&](size_t bytes) { size_t p = off; off = (off + bytes + 255) & ~(size_t)255; return p; };
    size_t o_flag   = alloc(4);
    size_t o_counts = alloc((size_t)NBMAX * 4);
    size_t o_offs   = alloc(((size_t)NBMAX + 1) * 4);
    size_t o_gcur   = alloc((size_t)NBMAX * 4);
    size_t o_recs   = alloc((size_t)num_edges * 8);
    size_t o_offs2  = alloc((((size_t)nbkt << RPB_SHIFT) + 1) * 4);
    size_t need_base = off;
    size_t o_hemb   = alloc((size_t)num_nodes * DIM * 2);   // fp16 table, 128 MB
    size_t need_f16 = off;

    char* ws = (char*)d_ws;
    int* flag = (int*)(ws + o_flag);

    detect_idx_width<<<1, 256, 0, stream>>>((const unsigned int*)eidx, flag);

    if (ws_size < need_base || nbkt > NBMAX || num_nodes > (1 << 20)) {
        hipMemsetAsync(d_out, 0, (size_t)out_size * sizeof(float), stream);
        long long total_threads = (long long)num_edges * 16;
        long long grid = (total_threads + 255) / 256;
        scatter_edges<<<(int)grid, 256, 0, stream>>>(
            eidx, vals, users, items, out, flag, num_users, num_edges);
        return;
    }

    int* counts  = (int*)(ws + o_counts);
    int* offs    = (int*)(ws + o_offs);
    int* gcursor = (int*)(ws + o_gcur);
    u64* recs    = (u64*)(ws + o_recs);
    int* offs2   = (int*)(ws + o_offs2);
    h4*  hemb4   = (h4*)(ws + o_hemb);

    bool use_f16 = (ws_size >= need_f16) &&
                   (((size_t)num_users * DIM % 4) == 0) && ((DIM % 4) == 0);

    hipMemsetAsync(counts, 0, (size_t)NBMAX * 4, stream);

    if (use_f16) {
        long long usz4 = (long long)num_users * DIM / 4;
        long long tot4 = (long long)num_nodes * DIM / 4;
        convert_emb<<<2048, 256, 0, stream>>>((const f4v*)users, (const f4v*)items,
                                              usz4, tot4, hemb4);
    }

    hist_coarse<<<1024, 256, 0, stream>>>(eidx, flag, counts, num_edges);
    scan512<<<1, 256, 0, stream>>>(counts, offs, gcursor, offs2, nbkt);

    int bin_grid = (num_edges + CHUNK - 1) / CHUNK;
    bin_edges<<<bin_grid, 256, 0, stream>>>(eidx, vals, flag, gcursor, recs, num_edges);

    sort_bucket<<<nbkt, 256, 0, stream>>>(offs, recs, offs2);

    if (use_f16) {
        int nodes_per_block = 16 * NPG;   // 16 groups x NPG nodes
        int gg = (num_nodes + nodes_per_block - 1) / nodes_per_block;
        gather_nodes_h<<<gg, 256, 0, stream>>>(offs, offs2, recs, hemb4, out, num_nodes);
    } else {
        int nodes_per_block = 256 / 64;  // 4 waves -> 4 nodes
        int gg = (num_nodes + nodes_per_block - 1) / nodes_per_block;
        const float* items_m = items - (size_t)num_users * DIM;
        gather_nodes<<<gg, 256, 0, stream>>>(offs, offs2, recs, users, items_m, out,
                                             num_users, num_nodes);
    }
}

// Round 2
// 487.342 us; speedup vs baseline: 1.4193x; 1.1839x over previous
//
#include <hip/hip_runtime.h>

#define DIM 64
#define RPB 2048              // rows per coarse bucket
#define RPB_SHIFT 11
#define NBMAX 512             // max coarse buckets supported
#define CHUNK 4096            // edges per bin_edges block
#define EPT 16                // edges per thread in bin_edges (CHUNK/256)
#define CAPT 70               // records per thread in sort (cap = 70*256 = 17920)
#define NPG 8                 // nodes per 8-lane group in gather

typedef unsigned long long u64;
typedef unsigned int u32;
typedef unsigned short u16;
typedef float f4v __attribute__((ext_vector_type(4)));
typedef _Float16 h4 __attribute__((ext_vector_type(4)));
typedef _Float16 h8 __attribute__((ext_vector_type(8)));

// ---------------- idx width detection (int64 vs int32 layout) --------------
__global__ void detect_idx_width(const unsigned int* __restrict__ idx_words,
                                 int* __restrict__ flag) {
    __shared__ unsigned int s_or[256];
    unsigned int acc = 0;
    for (int i = threadIdx.x; i < 4096; i += blockDim.x)
        acc |= idx_words[2 * i + 1];
    s_or[threadIdx.x] = acc;
    __syncthreads();
    for (int s = 128; s > 0; s >>= 1) {
        if (threadIdx.x < s) s_or[threadIdx.x] |= s_or[threadIdx.x + s];
        __syncthreads();
    }
    if (threadIdx.x == 0) *flag = (s_or[0] == 0) ? 1 : 0;
}

__device__ __forceinline__ int load_idx(const void* ei, int use64, long long i) {
    return use64 ? (int)((const long long*)ei)[i] : ((const int*)ei)[i];
}

// ---------------- embedding f32 -> f16 conversion (nt reads) ---------------
__global__ __launch_bounds__(256) void convert_emb(const f4v* __restrict__ u4,
                                                   const f4v* __restrict__ i4,
                                                   long long usz4, long long tot4,
                                                   h4* __restrict__ dst) {
    long long stride = (long long)gridDim.x * blockDim.x;
    for (long long idx = (long long)blockIdx.x * blockDim.x + threadIdx.x;
         idx < tot4; idx += stride) {
        const f4v* src = (idx < usz4) ? (u4 + idx) : (i4 + (idx - usz4));
        f4v f = __builtin_nontemporal_load(src);
        h4 o;
        o.x = (_Float16)f.x; o.y = (_Float16)f.y;
        o.z = (_Float16)f.z; o.w = (_Float16)f.w;
        dst[idx] = o;
    }
}

// ---------------- pass 1: coarse histogram (LDS-assisted, vectorized) ------
__global__ __launch_bounds__(256) void hist_coarse(const void* __restrict__ ei,
                                                   const int* __restrict__ flag,
                                                   int* __restrict__ counts,
                                                   int num_edges) {
    __shared__ int h[NBMAX];
    for (int b = threadIdx.x; b < NBMAX; b += 256) h[b] = 0;
    __syncthreads();
    int use64 = *flag;
    long long tid = (long long)blockIdx.x * 256 + threadIdx.x;
    long long stride = (long long)gridDim.x * 256;
    long long npairs = (long long)num_edges >> 1;
    if (use64) {
        const ulonglong2* p = (const ulonglong2*)ei;
        for (long long e = tid; e < npairs; e += stride) {
            ulonglong2 rr = p[e];
            atomicAdd(&h[(int)(u32)rr.x >> RPB_SHIFT], 1);
            atomicAdd(&h[(int)(u32)rr.y >> RPB_SHIFT], 1);
        }
    } else {
        const int2* p = (const int2*)ei;
        for (long long e = tid; e < npairs; e += stride) {
            int2 rr = p[e];
            atomicAdd(&h[rr.x >> RPB_SHIFT], 1);
            atomicAdd(&h[rr.y >> RPB_SHIFT], 1);
        }
    }
    if (tid == 0 && (num_edges & 1)) {
        int r = load_idx(ei, use64, num_edges - 1);
        atomicAdd(&h[r >> RPB_SHIFT], 1);
    }
    __syncthreads();
    for (int b = threadIdx.x; b < NBMAX; b += 256)
        if (h[b]) atomicAdd(&counts[b], h[b]);
}

// ---------------- pass 2: scan of 512 bucket counts (1 block) --------------
__global__ __launch_bounds__(256) void scan512(const int* __restrict__ counts,
                                               int* __restrict__ offs,
                                               int* __restrict__ gcursor,
                                               int* __restrict__ offs2, int nbkt) {
    __shared__ int ps[256];
    int t = threadIdx.x;
    int h0 = counts[2 * t], h1 = counts[2 * t + 1];
    ps[t] = h0 + h1;
    __syncthreads();
    for (int st = 1; st < 256; st <<= 1) {
        int add = (t >= st) ? ps[t - st] : 0;
        __syncthreads();
        ps[t] += add;
        __syncthreads();
    }
    int ep = (t > 0) ? ps[t - 1] : 0;
    offs[2 * t] = ep;          gcursor[2 * t] = ep;
    offs[2 * t + 1] = ep + h0; gcursor[2 * t + 1] = ep + h0;
    if (t == 255) {
        offs[NBMAX] = ps[255];
        offs2[(long long)nbkt << RPB_SHIFT] = ps[255];   // tail sentinel = num_edges
    }
}

// ---------------- pass 3: LDS-staged coarse binning ------------------------
// record: [w:32][rowlocal:11][col:20]
__global__ __launch_bounds__(256) void bin_edges(const void* __restrict__ ei,
                                                 const float* __restrict__ vals,
                                                 const int* __restrict__ flag,
                                                 int* __restrict__ gcursor,
                                                 u64* __restrict__ recs,
                                                 int num_edges) {
    __shared__ u32 hist[NBMAX];     // counts, then running cursor
    __shared__ u32 scanL[NBMAX];
    __shared__ u32 gbase[NBMAX];
    __shared__ u32 ps[256];
    __shared__ u64 payload[CHUNK];
    __shared__ u16 bidv[CHUNK];

    int tid = threadIdx.x;
    long long base = (long long)blockIdx.x * CHUNK;
    int n = (int)min((long long)CHUNK, (long long)num_edges - base);
    int use64 = *flag;

    for (int b = tid; b < NBMAX; b += 256) hist[b] = 0;
    __syncthreads();

    int rows_[EPT]; int cols_[EPT]; float ws_[EPT];
    #pragma unroll
    for (int i = 0; i < EPT; ++i) {
        int j = tid + i * 256;
        rows_[i] = -1;
        if (j < n) {
            long long e = base + j;
            rows_[i] = load_idx(ei, use64, e);
            cols_[i] = load_idx(ei, use64, (long long)num_edges + e);
            ws_[i]   = vals[e];
            atomicAdd(&hist[rows_[i] >> RPB_SHIFT], 1u);
        }
    }
    __syncthreads();

    // exclusive scan of 512 counts (pair-per-thread Hillis-Steele)
    u32 h0 = hist[2 * tid], h1 = hist[2 * tid + 1];
    ps[tid] = h0 + h1;
    __syncthreads();
    for (int st = 1; st < 256; st <<= 1) {
        u32 add = (tid >= st) ? ps[tid - st] : 0;
        __syncthreads();
        ps[tid] += add;
        __syncthreads();
    }
    u32 ep = (tid > 0) ? ps[tid - 1] : 0;
    scanL[2 * tid] = ep;
    scanL[2 * tid + 1] = ep + h0;
    __syncthreads();

    // reserve global space per bucket
    for (int b = tid; b < NBMAX; b += 256) {
        u32 c = hist[b];
        gbase[b] = c ? (u32)atomicAdd(&gcursor[b], (int)c) : 0u;
    }
    __syncthreads();
    for (int b = tid; b < NBMAX; b += 256) hist[b] = scanL[b];
    __syncthreads();

    // scatter records into LDS ordered by bucket
    #pragma unroll
    for (int i = 0; i < EPT; ++i) {
        if (rows_[i] >= 0) {
            int b = rows_[i] >> RPB_SHIFT;
            u32 pos = atomicAdd(&hist[b], 1u);
            u32 rl = (u32)(rows_[i] & (RPB - 1));
            payload[pos] = ((u64)__float_as_uint(ws_[i]) << 32) | (rl << 20) | (u32)cols_[i];
            bidv[pos] = (u16)b;
        }
    }
    __syncthreads();

    // flush: consecutive LDS slots -> consecutive global slots per bucket run
    for (int j = tid; j < n; j += 256) {
        u64 rec = payload[j];
        int b = bidv[j];
        recs[gbase[b] + (u32)j - scanL[b]] = rec;
    }
}

// ---------------- pass 4: per-bucket exact sort (register-staged) ----------
__global__ __launch_bounds__(256, 1) void sort_bucket(const int* __restrict__ offs,
                                                      u64* __restrict__ recs,
                                                      int* __restrict__ offs2) {
    __shared__ u32 bins[RPB];    // 8 KB
    __shared__ u32 ps[256];
    int b = blockIdx.x;
    int t = threadIdx.x;
    int beg = offs[b], end = offs[b + 1];
    int cnt = end - beg;
    int row0 = b << RPB_SHIFT;

    if (cnt > CAPT * 256) {
        // practically unreachable; leave coarse-sorted, sentinel offsets
        for (int i = t; i < RPB; i += 256) offs2[row0 + i] = -(b + 1);
        return;
    }

    // stage the whole bucket in registers (static indexing -> stays in VGPRs)
    u64 r_[CAPT];
    #pragma unroll
    for (int k = 0; k < CAPT; ++k) {
        int j = t + k * 256;
        r_[k] = (j < cnt) ? recs[beg + j] : 0ull;
    }
    for (int i = t; i < RPB; i += 256) bins[i] = 0;
    __syncthreads();

    #pragma unroll
    for (int k = 0; k < CAPT; ++k) {
        int j = t + k * 256;
        if (j < cnt) atomicAdd(&bins[(u32)(r_[k] >> 20) & (RPB - 1)], 1u);
    }
    __syncthreads();

    // scan 2048 bins: thread owns 8 consecutive
    u32 c0[8]; u32 s = 0;
    #pragma unroll
    for (int i = 0; i < 8; ++i) { c0[i] = bins[t * 8 + i]; s += c0[i]; }
    ps[t] = s;
    __syncthreads();
    for (int st = 1; st < 256; st <<= 1) {
        u32 add = (t >= st) ? ps[t - st] : 0;
        __syncthreads();
        ps[t] += add;
        __syncthreads();
    }
    u32 ex = (t > 0) ? ps[t - 1] : 0;
    #pragma unroll
    for (int i = 0; i < 8; ++i) {
        bins[t * 8 + i] = ex;
        offs2[row0 + t * 8 + i] = beg + (int)ex;
        ex += c0[i];
    }
    __syncthreads();

    // in-place scatter to exact positions (all records already in registers)
    #pragma unroll
    for (int k = 0; k < CAPT; ++k) {
        int j = t + k * 256;
        if (j < cnt) {
            u32 rl = (u32)(r_[k] >> 20) & (RPB - 1);
            u32 pos = atomicAdd(&bins[rl], 1u);
            recs[beg + pos] = r_[k];
        }
    }
}

// ---------------- pass 5 (fp16 table): one 8-lane group per node strip -----
// Lane l8 owns dims [8*l8, 8*l8+8) -> one dwordx4 table load per edge per
// lane (16 B/lane = coalescing sweet spot; each table-load instr serves 8
// edges across the wave's 8 groups). Unroll 8 = mean degree: one burst of
// 8 rec loads -> 8 table loads keeps ~16 loads in flight per group. Node
// offsets are prefetched once per strip via lane-parallel load + shfl.
#define ACC8(P0, P1, W, V) \
    P0.x += W * (float)V[0]; P0.y += W * (float)V[1]; \
    P0.z += W * (float)V[2]; P0.w += W * (float)V[3]; \
    P1.x += W * (float)V[4]; P1.y += W * (float)V[5]; \
    P1.z += W * (float)V[6]; P1.w += W * (float)V[7];

__global__ __launch_bounds__(256) void gather_nodes_h(const int* __restrict__ offs,
                                                      const int* __restrict__ offs2,
                                                      const u64* __restrict__ recs,
                                                      const h8* __restrict__ hemb8,
                                                      float* __restrict__ out,
                                                      int num_nodes) {
    int lane = threadIdx.x & 63;
    int l8   = lane & 7;
    int g    = threadIdx.x >> 3;               // group id in block: 0..31
    int n0   = (blockIdx.x * 32 + g) * NPG;
    int gbl  = lane & ~7;                      // group base lane within wave
    if (n0 >= num_nodes) return;

    // strip-wide offset prefetch: lane l8 covers node n0+l8
    int begL = 0, endL = 0;
    int nl = n0 + l8;
    if (nl < num_nodes) { begL = offs2[nl]; endL = offs2[nl + 1]; }

    for (int nn = 0; nn < NPG; ++nn) {
        int node = n0 + nn;
        if (node >= num_nodes) return;
        int beg = __shfl(begL, gbl + nn, 64);
        int end = __shfl(endL, gbl + nn, 64);
        if (beg < 0) { int b = node >> RPB_SHIFT; beg = offs[b]; end = offs[b + 1]; }
        else if (end < 0) { end = offs[(node >> RPB_SHIFT) + 1]; }
        u32 rl = (u32)(node & (RPB - 1));

        float4 p0 = make_float4(0.f,0.f,0.f,0.f), p1 = make_float4(0.f,0.f,0.f,0.f);
        float4 q0 = make_float4(0.f,0.f,0.f,0.f), q1 = make_float4(0.f,0.f,0.f,0.f);
        int last = end - 1;

        for (int i = beg; i < end; i += 8) {
            int e1 = min(i + 1, last), e2 = min(i + 2, last);
            int e3 = min(i + 3, last), e4 = min(i + 4, last);
            int e5 = min(i + 5, last), e6 = min(i + 6, last);
            int e7 = min(i + 7, last);
            u64 s0 = recs[i];  u64 s1 = recs[e1];
            u64 s2 = recs[e2]; u64 s3 = recs[e3];
            u64 s4 = recs[e4]; u64 s5 = recs[e5];
            u64 s6 = recs[e6]; u64 s7 = recs[e7];

            h8 v0 = hemb8[(((u32)s0 & 0xFFFFFu) << 3) + l8];
            h8 v1 = hemb8[(((u32)s1 & 0xFFFFFu) << 3) + l8];
            h8 v2 = hemb8[(((u32)s2 & 0xFFFFFu) << 3) + l8];
            h8 v3 = hemb8[(((u32)s3 & 0xFFFFFu) << 3) + l8];
            h8 v4 = hemb8[(((u32)s4 & 0xFFFFFu) << 3) + l8];
            h8 v5 = hemb8[(((u32)s5 & 0xFFFFFu) << 3) + l8];
            h8 v6 = hemb8[(((u32)s6 & 0xFFFFFu) << 3) + l8];
            h8 v7 = hemb8[(((u32)s7 & 0xFFFFFu) << 3) + l8];

            u32 rm = RPB - 1;
            // slot 0 always in-bounds; clamped dups belong to this node's
            // last record (r==rl) so the bound check must mask them.
            float w0 = ((((u32)(s0 >> 20)) & rm) == rl)
                       ? __uint_as_float((u32)(s0 >> 32)) : 0.f;
            float w1 = (((((u32)(s1 >> 20)) & rm) == rl) & (i + 1 < end))
                       ? __uint_as_float((u32)(s1 >> 32)) : 0.f;
            float w2 = (((((u32)(s2 >> 20)) & rm) == rl) & (i + 2 < end))
                       ? __uint_as_float((u32)(s2 >> 32)) : 0.f;
            float w3 = (((((u32)(s3 >> 20)) & rm) == rl) & (i + 3 < end))
                       ? __uint_as_float((u32)(s3 >> 32)) : 0.f;
            float w4 = (((((u32)(s4 >> 20)) & rm) == rl) & (i + 4 < end))
                       ? __uint_as_float((u32)(s4 >> 32)) : 0.f;
            float w5 = (((((u32)(s5 >> 20)) & rm) == rl) & (i + 5 < end))
                       ? __uint_as_float((u32)(s5 >> 32)) : 0.f;
            float w6 = (((((u32)(s6 >> 20)) & rm) == rl) & (i + 6 < end))
                       ? __uint_as_float((u32)(s6 >> 32)) : 0.f;
            float w7 = (((((u32)(s7 >> 20)) & rm) == rl) & (i + 7 < end))
                       ? __uint_as_float((u32)(s7 >> 32)) : 0.f;

            ACC8(p0, p1, w0, v0);
            ACC8(q0, q1, w1, v1);
            ACC8(p0, p1, w2, v2);
            ACC8(q0, q1, w3, v3);
            ACC8(p0, p1, w4, v4);
            ACC8(q0, q1, w5, v5);
            ACC8(p0, p1, w6, v6);
            ACC8(q0, q1, w7, v7);
        }

        p0.x += q0.x; p0.y += q0.y; p0.z += q0.z; p0.w += q0.w;
        p1.x += q1.x; p1.y += q1.y; p1.z += q1.z; p1.w += q1.w;

        f4v o0; o0.x = p0.x; o0.y = p0.y; o0.z = p0.z; o0.w = p0.w;
        f4v o1; o1.x = p1.x; o1.y = p1.y; o1.z = p1.z; o1.w = p1.w;
        f4v* dst = (f4v*)out + ((long long)node << 4) + (l8 << 1);
        __builtin_nontemporal_store(o0, dst);
        __builtin_nontemporal_store(o1, dst + 1);
    }
}

// ---------------- pass 5 (f32 fallback): one wave per node -----------------
__device__ __forceinline__ void gstep(u64 s, u32 rl,
                                      const float* __restrict__ users,
                                      const float* __restrict__ items_m,
                                      int num_users, int l16, float4& a) {
    int c = (int)(s & 0xFFFFFu);
    float w = __uint_as_float((u32)(s >> 32));
    w = (((u32)(s >> 20) & (RPB - 1)) == rl) ? w : 0.f;
    const float* p = ((c < num_users) ? users : items_m) + ((u32)c << 6);
    float4 m = reinterpret_cast<const float4*>(p)[l16];
    a.x += w * m.x; a.y += w * m.y; a.z += w * m.z; a.w += w * m.w;
}

__global__ __launch_bounds__(256) void gather_nodes(const int* __restrict__ offs,
                                                    const int* __restrict__ offs2,
                                                    const u64* __restrict__ recs,
                                                    const float* __restrict__ users,
                                                    const float* __restrict__ items_m,
                                                    float* __restrict__ out,
                                                    int num_users, int num_nodes) {
    int node = blockIdx.x * (blockDim.x >> 6) + (threadIdx.x >> 6);
    int lane = threadIdx.x & 63;
    if (node >= num_nodes) return;
    int q   = lane >> 4;
    int l16 = lane & 15;

    int beg = offs2[node];
    int end = offs2[node + 1];
    if (beg < 0) { int b = node >> RPB_SHIFT; beg = offs[b]; end = offs[b + 1]; }
    else if (end < 0) { end = offs[(node >> RPB_SHIFT) + 1]; }
    u32 rl = (u32)(node & (RPB - 1));

    float4 a0 = make_float4(0.f, 0.f, 0.f, 0.f);
    float4 a1 = make_float4(0.f, 0.f, 0.f, 0.f);

    int i = beg + q;
    for (; i + 4 < end; i += 8) {
        u64 s0 = recs[i];
        u64 s1 = recs[i + 4];
        gstep(s0, rl, users, items_m, num_users, l16, a0);
        gstep(s1, rl, users, items_m, num_users, l16, a1);
    }
    if (i < end) {
        u64 s0 = recs[i];
        gstep(s0, rl, users, items_m, num_users, l16, a0);
    }
    a0.x += a1.x; a0.y += a1.y; a0.z += a1.z; a0.w += a1.w;

    for (int msk = 16; msk <= 32; msk <<= 1) {
        a0.x += __shfl_xor(a0.x, msk, 64);
        a0.y += __shfl_xor(a0.y, msk, 64);
        a0.z += __shfl_xor(a0.z, msk, 64);
        a0.w += __shfl_xor(a0.w, msk, 64);
    }
    if (q == 0)
        reinterpret_cast<float4*>(out)[(long long)node * 16 + l16] = a0;
}

// ---------------- fallback: R1 atomic scatter ------------------------------
__global__ __launch_bounds__(256) void scatter_edges(const void* __restrict__ edge_index,
                                                     const float* __restrict__ vals,
                                                     const float* __restrict__ users,
                                                     const float* __restrict__ items,
                                                     float* __restrict__ out,
                                                     const int* __restrict__ idx64_flag,
                                                     int num_users, int num_edges) {
    long long gid = (long long)blockIdx.x * blockDim.x + threadIdx.x;
    long long e = gid >> 4;
    int lane = (int)(gid & 15);
    if (e >= num_edges) return;
    int use64 = *idx64_flag;
    int r = load_idx(edge_index, use64, e);
    int c = load_idx(edge_index, use64, (long long)num_edges + e);
    float w = vals[e];
    const float* src = (c < num_users)
        ? (users + (long long)c * DIM)
        : (items + (long long)(c - num_users) * DIM);
    float4 m = reinterpret_cast<const float4*>(src)[lane];
    float* dst = out + (long long)r * DIM + lane * 4;
    unsafeAtomicAdd(dst + 0, m.x * w);
    unsafeAtomicAdd(dst + 1, m.y * w);
    unsafeAtomicAdd(dst + 2, m.z * w);
    unsafeAtomicAdd(dst + 3, m.w * w);
}

extern "C" void kernel_launch(void* const* d_in, const int* in_sizes, int n_in,
                              void* d_out, int out_size, void* d_ws, size_t ws_size,
                              hipStream_t stream) {
    const float* users = (const float*)d_in[0];
    const float* items = (const float*)d_in[1];
    const void*  eidx  = d_in[2];
    const float* vals  = (const float*)d_in[3];
    float* out = (float*)d_out;

    int num_users = in_sizes[0] / DIM;               // 600000
    int num_items = in_sizes[1] / DIM;               // 400000
    int num_nodes = num_users + num_items;           // 1000000
    int num_edges = in_sizes[3];                     // 8000000
    int nbkt = (num_nodes + RPB - 1) >> RPB_SHIFT;   // 489

    // workspace layout
    size_t off = 0;
    auto alloc = [&](size_t bytes) { size_t p = off; off = (off + bytes + 255) & ~(size_t)255; return p; };
    size_t o_flag   = alloc(4);
    size_t o_counts = alloc((size_t)NBMAX * 4);
    size_t o_offs   = alloc(((size_t)NBMAX + 1) * 4);
    size_t o_gcur   = alloc((size_t)NBMAX * 4);
    size_t o_recs   = alloc((size_t)num_edges * 8 + 64);   // +64: unroll over-read pad
    size_t o_offs2  = alloc((((size_t)nbkt << RPB_SHIFT) + 1) * 4);
    size_t need_base = off;
    size_t o_hemb   = alloc((size_t)num_nodes * DIM * 2);   // fp16 table, 128 MB
    size_t need_f16 = off;

    char* ws = (char*)d_ws;
    int* flag = (int*)(ws + o_flag);

    detect_idx_width<<<1, 256, 0, stream>>>((const unsigned int*)eidx, flag);

    if (ws_size < need_base || nbkt > NBMAX || num_nodes > (1 << 20)) {
        hipMemsetAsync(d_out, 0, (size_t)out_size * sizeof(float), stream);
        long long total_threads = (long long)num_edges * 16;
        long long grid = (total_threads + 255) / 256;
        scatter_edges<<<(int)grid, 256, 0, stream>>>(
            eidx, vals, users, items, out, flag, num_users, num_edges);
        return;
    }

    int* counts  = (int*)(ws + o_counts);
    int* offs    = (int*)(ws + o_offs);
    int* gcursor = (int*)(ws + o_gcur);
    u64* recs    = (u64*)(ws + o_recs);
    int* offs2   = (int*)(ws + o_offs2);
    h4*  hemb4   = (h4*)(ws + o_hemb);

    bool use_f16 = (ws_size >= need_f16) &&
                   (((size_t)num_users * DIM % 4) == 0) && ((DIM % 4) == 0);

    hipMemsetAsync(counts, 0, (size_t)NBMAX * 4, stream);

    if (use_f16) {
        long long usz4 = (long long)num_users * DIM / 4;
        long long tot4 = (long long)num_nodes * DIM / 4;
        convert_emb<<<2048, 256, 0, stream>>>((const f4v*)users, (const f4v*)items,
                                              usz4, tot4, hemb4);
    }

    hist_coarse<<<1024, 256, 0, stream>>>(eidx, flag, counts, num_edges);
    scan512<<<1, 256, 0, stream>>>(counts, offs, gcursor, offs2, nbkt);

    int bin_grid = (num_edges + CHUNK - 1) / CHUNK;
    bin_edges<<<bin_grid, 256, 0, stream>>>(eidx, vals, flag, gcursor, recs, num_edges);

    sort_bucket<<<nbkt, 256, 0, stream>>>(offs, recs, offs2);

    if (use_f16) {
        int nodes_per_block = 32 * NPG;   // 32 groups x NPG nodes
        int gg = (num_nodes + nodes_per_block - 1) / nodes_per_block;
        gather_nodes_h<<<gg, 256, 0, stream>>>(offs, offs2, recs,
                                               (const h8*)hemb4, out, num_nodes);
    } else {
        int nodes_per_block = 256 / 64;  // 4 waves -> 4 nodes
        int gg = (num_nodes + nodes_per_block - 1) / nodes_per_block;
        const float* items_m = items - (size_t)num_users * DIM;
        gather_nodes<<<gg, 256, 0, stream>>>(offs, offs2, recs, users, items_m, out,
                                             num_users, num_nodes);
    }
}